// Round 11
// baseline (460.672 us; speedup 1.0000x reference)
//
#include <hip/hip_runtime.h>
#include <hip/hip_bf16.h>

// Llama4 Vision Attention, MI355X bf16-MFMA pipeline.
// B=16 S=576 E=1408 H=16 D=88 (pad 96). fp32 in/out, bf16 internal compute.
// R11: gemm<0> replaced by 8-phase 256^2 deep-pipelined GEMM (T3+T4+T5,
//      counted vmcnt(2), 216-block single-wave grid); attn gets T14
//      async-STAGE split (loads for t+1 issued under compute of t).

typedef unsigned short UST;
typedef __attribute__((ext_vector_type(8))) __bf16 bf16x8;
typedef __attribute__((ext_vector_type(4))) float f32x4;
typedef __attribute__((ext_vector_type(8))) UST us8;
typedef __attribute__((ext_vector_type(4))) UST us4;

typedef __attribute__((address_space(3))) unsigned int lds_u32;
typedef const __attribute__((address_space(1))) unsigned int glob_u32;

static __device__ __forceinline__ float bf2f(UST u){
  unsigned int x = ((unsigned int)u) << 16;
  return __builtin_bit_cast(float, x);
}
static __device__ __forceinline__ UST f2bf(float f){
  unsigned int x = __builtin_bit_cast(unsigned int, f);
  x += 0x7fffu + ((x >> 16) & 1u);   // RN-even; inputs finite
  return (UST)(x >> 16);
}

// ------ RoPE table, interleaved {cos,sin}[576][44] (f64 math, s-major) ------
__global__ void k_tables(float* __restrict__ cs2){
  int s = blockIdx.x;
  int p = threadIdx.x;
  if (p >= 44) return;
  int tt = p % 22;
  double comp = (p < 22) ? (double)(s % 24 + 1) : (double)(s / 24 + 1);
  double a = comp * pow(10000.0, -(double)tt / 22.0);
  cs2[s*88 + 2*p]     = (float)cos(a);
  cs2[s*88 + 2*p + 1] = (float)sin(a);
}

// ------ zero pads: qa/ka cols 88..95 per row; vt rows d=88..95 --------------
__global__ void k_zero(UST* __restrict__ qa, UST* __restrict__ ka, UST* __restrict__ vt){
  int c = blockIdx.x*256 + threadIdx.x;        // 0..147455 = 256bh * 576
  int bh = c / 576, s = c - bh*576;
  us8 z = {0,0,0,0,0,0,0,0};
  *(us8*)(qa + ((size_t)bh*576 + s)*96 + 88) = z;
  *(us8*)(ka + ((size_t)bh*576 + s)*96 + 88) = z;
  *(us8*)(vt + (size_t)bh*55296 + 50688 + s*8) = z;   // rows 88..95 of [96][576]
}

// ---------------- fp32 -> bf16 cast (vectorized) ----------------------------
__global__ void k_cvt(const float* __restrict__ in, UST* __restrict__ out, int n4){
  int i = blockIdx.x * 256 + threadIdx.x;
  if (i >= n4) return;
  float4 v = ((const float4*)in)[i];
  us4 o; o[0]=f2bf(v.x); o[1]=f2bf(v.y); o[2]=f2bf(v.z); o[3]=f2bf(v.w);
  *(us4*)(out + 4*(size_t)i) = o;
}

// ---------------- fp32 [K][N] -> bf16 [N][K] transpose-convert --------------
// grid.y spans Npad/64; blocks with nt*64 >= N zero-fill (no OOB W reads).
__global__ void k_cvt_t(const float* __restrict__ W, UST* __restrict__ Bt, int K, int N){
  __shared__ __align__(16) UST tl[64][70];  // odd dword stride -> low conflict
  int kt = blockIdx.x, nt = blockIdx.y;
  int t = threadIdx.x;
  int u = t & 3;
  int n = t >> 2;
  UST* dst = Bt + (size_t)(nt*64 + n)*K + kt*64 + u*16;
  if (nt*64 >= N){              // pad region: zero-fill
    us8 z = {0,0,0,0,0,0,0,0};
    *(us8*)(dst) = z; *(us8*)(dst + 8) = z;
    return;
  }
  int k = t >> 2;
  const float* src = W + (size_t)(kt*64 + k)*N + nt*64 + u*16;
#pragma unroll
  for (int i = 0; i < 4; ++i){
    float4 v = *(const float4*)(src + 4*i);
    UST* d = &tl[k][u*16 + 4*i];
    d[0]=f2bf(v.x); d[1]=f2bf(v.y); d[2]=f2bf(v.z); d[3]=f2bf(v.w);
  }
  __syncthreads();
#pragma unroll
  for (int i = 0; i < 2; ++i){
    us8 o;
#pragma unroll
    for (int j = 0; j < 8; ++j) o[j] = tl[u*16 + 8*i + j][n];
    *(us8*)(dst + 8*i) = o;
  }
}

// ---------------- bf16 GEMM (round-2 proven body), QKV fused epilogue -------
// (Same as R10's EPI=3: LDS-staged coalesced epilogue, rope in-register.)
__global__ __launch_bounds__(256, 2) void k_gemmqkv(
    const UST* __restrict__ A, const UST* __restrict__ Bt,
    const float* __restrict__ bias,
    int M, int N, int K,
    UST* __restrict__ qa, UST* __restrict__ ka, UST* __restrict__ vt,
    const float* __restrict__ cs2)
{
  __shared__ __align__(16) char SMEM[65536];
  UST (*lA)[128][64] = reinterpret_cast<UST(*)[128][64]>(SMEM);          // [2]
  UST (*lB)[128][64] = reinterpret_cast<UST(*)[128][64]>(SMEM + 32768);  // [2]
  float* sm = reinterpret_cast<float*>(SMEM);                            // [128][128]

  const int t = threadIdx.x;
  const int bm = blockIdx.x, bn = blockIdx.y;
  const int wave = t >> 6, lane = t & 63;
  const int lm = lane & 15, g = lane >> 4;
  const int wr = (wave >> 1) << 6, wc = (wave & 1) << 6;
  const int lrow = lane >> 3;                       // 0..7 within 8-row chunk
  const int lcol = (((lane & 7) ^ lrow) << 3);      // pre-swizzled source col
  const UST* Ag = A  + (size_t)(bm*128 + wave*32 + lrow)*K + lcol;
  const UST* Bg = Bt + (size_t)(bn*128 + wave*32 + lrow)*K + lcol;

  f32x4 zero = {0.f,0.f,0.f,0.f};
  f32x4 acc[4][4];
#pragma unroll
  for (int i=0;i<4;++i)
#pragma unroll
    for (int j=0;j<4;++j) acc[i][j] = zero;

  const int nkt = K >> 6;
  auto stage = [&](int kt, int buf){
#pragma unroll
    for (int c = 0; c < 4; ++c){
      __builtin_amdgcn_global_load_lds((glob_u32*)(Ag + (size_t)kt*64 + (size_t)(8*c)*K),
                                       (lds_u32*)(&lA[buf][wave*32 + 8*c][0]), 16, 0, 0);
      __builtin_amdgcn_global_load_lds((glob_u32*)(Bg + (size_t)kt*64 + (size_t)(8*c)*K),
                                       (lds_u32*)(&lB[buf][wave*32 + 8*c][0]), 16, 0, 0);
    }
  };

  stage(0, 0);
  __syncthreads();
  const int swz = (lm & 7) << 3;

  for (int kt = 0; kt < nkt; ++kt){
    const int cur = kt & 1;
    if (kt + 1 < nkt) stage(kt + 1, cur ^ 1);
#pragma unroll
    for (int ks = 0; ks < 2; ++ks){
      bf16x8 af[4], bfv[4];
      const int cb = (ks*32 + g*8) ^ swz;
#pragma unroll
      for (int mf = 0; mf < 4; ++mf)
        af[mf] = __builtin_bit_cast(bf16x8, *(const us8*)&lA[cur][wr + mf*16 + lm][cb]);
#pragma unroll
      for (int nf = 0; nf < 4; ++nf)
        bfv[nf] = __builtin_bit_cast(bf16x8, *(const us8*)&lB[cur][wc + nf*16 + lm][cb]);
#pragma unroll
      for (int mf = 0; mf < 4; ++mf)
#pragma unroll
        for (int nf = 0; nf < 4; ++nf)
          acc[mf][nf] = __builtin_amdgcn_mfma_f32_16x16x32_bf16(af[mf], bfv[nf], acc[mf][nf], 0, 0, 0);
    }
    __syncthreads();
  }

  // ---- stage acc+bias into swizzled sm[128][128] (lA/lB dead) ----
#pragma unroll
  for (int nf = 0; nf < 4; ++nf){
    const int col = wc + nf*16 + lm;
    const float bv = bias[bn*128 + col];
#pragma unroll
    for (int mf = 0; mf < 4; ++mf){
#pragma unroll
      for (int r = 0; r < 4; ++r){
        const int row = wr + mf*16 + g*4 + r;
        const int colS = (((col >> 3) ^ (row & 7)) << 3) | (col & 7);
        sm[row*128 + colS] = acc[mf][nf][r] + bv;
      }
    }
  }
  __syncthreads();

  const int j = bn / 11;               // 0 q, 1 k, 2 v (uniform per block)
  const int bnr = bn - j*11;
  if (j == 2){
#pragma unroll
    for (int i = 0; i < 8; ++i){
      const int idx = t + 256*i;
      const int col = idx & 127, rch = idx >> 7;
      const int cv = bnr*128 + col;
      const int h = cv / 88, dv = cv - h*88;
      const int s0g = bm*128 + rch*8;
      const int b2 = s0g / 576, sl = s0g - b2*576;
      us8 o;
#pragma unroll
      for (int k = 0; k < 8; ++k){
        const int row = rch*8 + k;
        const int colS = (((col >> 3) ^ (row & 7)) << 3) | (col & 7);
        o[k] = f2bf(sm[row*128 + colS]);
      }
      *(us8*)(vt + ((size_t)(b2*16 + h)*96 + dv)*576 + sl) = o;
    }
  } else {
    UST* outp = j ? ka : qa;
    const float sc = j ? 1.0f : 0.10660035817780521f;   // 88^-0.5 into q
#pragma unroll
    for (int i = 0; i < 8; ++i){
      const int idx = t + 256*i;
      const int ch = idx & 15, rr = idx >> 4;
      const int cv = bnr*128 + ch*8;
      const int h = cv / 88, d0 = cv - h*88;
      const int rb = bm*128 + rr;
      const int b2 = rb / 576, s = rb - b2*576;
      const float* src = &sm[rr*128 + ((ch ^ (rr & 7)) << 3)];
      float x[8];
#pragma unroll
      for (int k = 0; k < 8; ++k) x[k] = src[k];
      const float* tb = cs2 + s*88 + d0;
      float4 q0 = *(const float4*)(tb);
      float4 q1 = *(const float4*)(tb + 4);
      float cc[4]  = {q0.x, q0.z, q1.x, q1.z};
      float ssv[4] = {q0.y, q0.w, q1.y, q1.w};
      us8 o;
#pragma unroll
      for (int p = 0; p < 4; ++p){
        float o0 = (x[2*p]*cc[p]  - x[2*p+1]*ssv[p]) * sc;
        float o1 = (x[2*p]*ssv[p] + x[2*p+1]*cc[p])  * sc;
        o[2*p] = f2bf(o0); o[2*p+1] = f2bf(o1);
      }
      *(us8*)(outp + ((size_t)(b2*16 + h)*576 + s)*96 + d0) = o;
    }
  }
}

// ---------------- 8-phase 256^2 deep-pipelined GEMM (fp32 out + bias) -------
// 512 thr = 8 waves (2M x 4N), per-wave C 128x64, BK=64, LDS 128KB dbuf.
// Per phase: stage 1 half-tile (2 gload_lds) || 12 ds_read_b128 || 16 MFMA
// (one C-quadrant, setprio-wrapped), 2 barriers. vmcnt(2) once per K-tile
// (never 0 mid-loop): tile T's 8 loads issued across T-1's 4 phases; at T's
// phase-0 issue 2 more then retire exactly the 8 oldest. Chunk-XOR swizzle
// chunk^(row&7) on both stage-source and read (proven involution).
__global__ __launch_bounds__(512, 1) void k_gemm8p(
    const UST* __restrict__ A, const UST* __restrict__ Bt,
    const float* __restrict__ bias, float* __restrict__ C,
    int M, int N, int K)
{
  __shared__ __align__(16) UST lA[2][256][64];   // 64KB
  __shared__ __align__(16) UST lB[2][256][64];   // 64KB
  const int t = threadIdx.x;
  const int wave = t >> 6, lane = t & 63;
  const int lm = lane & 15, g = lane >> 4;
  const int wm = wave >> 2, wn = wave & 3;
  const int bm = blockIdx.x, bn = blockIdx.y;
  const int nkt = K >> 6;

  const int lr8 = lane >> 3;                       // 0..7 row within 8-row chunk
  const int schunk = ((lane & 7) ^ lr8) << 3;      // pre-swizzled source col (elems)

  // stage half h of tile tt2 into buf tt2&1; h: 0=A0,1=A1,2=B0,3=B1
  auto stage = [&](int tt2, int h){
    const int s = tt2 & 1;
    const int rb0 = (h & 1)*128 + wave*8;
    const UST* src = (h < 2) ? A : Bt;
    const int base = ((h < 2) ? bm : bn)*256;
#pragma unroll
    for (int j = 0; j < 2; ++j){
      const int rl = rb0 + j*64;
      UST* ldst = (h < 2) ? &lA[s][rl][0] : &lB[s][rl][0];
      __builtin_amdgcn_global_load_lds(
        (glob_u32*)(src + (size_t)(base + rl + lr8)*K + tt2*64 + schunk),
        (lds_u32*)ldst, 16, 0, 0);
    }
  };

  f32x4 zero = {0.f,0.f,0.f,0.f};
  f32x4 acc[8][4];
#pragma unroll
  for (int i=0;i<8;++i)
#pragma unroll
    for (int j=0;j<4;++j) acc[i][j] = zero;

  // prologue: all 4 halves of tile 0 (8 loads/thread)
#pragma unroll
  for (int h = 0; h < 4; ++h) stage(0, h);

  const int sw7 = lm & 7;

  for (int tt = 0; tt < nkt; ++tt){
    const int s = tt & 1;
#pragma unroll
    for (int q = 0; q < 4; ++q){
      if (tt + 1 < nkt) stage(tt + 1, q);
      if (q == 0){
        if (tt + 1 < nkt) asm volatile("s_waitcnt vmcnt(2)" ::: "memory");
        else              asm volatile("s_waitcnt vmcnt(0)" ::: "memory");
        __builtin_amdgcn_sched_barrier(0);
      }
      __builtin_amdgcn_s_barrier();

      const int qm = q >> 1, qn = q & 1;
      bf16x8 af[4][2], bfr[2][2];
#pragma unroll
      for (int ks = 0; ks < 2; ++ks){
        const int cb = (((ks << 2) | g) ^ sw7) << 3;
#pragma unroll
        for (int mf = 0; mf < 4; ++mf)
          af[mf][ks] = __builtin_bit_cast(bf16x8,
            *(const us8*)&lA[s][wm*128 + (qm*4 + mf)*16 + lm][cb]);
#pragma unroll
        for (int nf = 0; nf < 2; ++nf)
          bfr[nf][ks] = __builtin_bit_cast(bf16x8,
            *(const us8*)&lB[s][wn*64 + (qn*2 + nf)*16 + lm][cb]);
      }
      __builtin_amdgcn_s_setprio(1);
#pragma unroll
      for (int mf = 0; mf < 4; ++mf)
#pragma unroll
        for (int nf = 0; nf < 2; ++nf)
#pragma unroll
          for (int ks = 0; ks < 2; ++ks)
            acc[qm*4 + mf][qn*2 + nf] =
              __builtin_amdgcn_mfma_f32_16x16x32_bf16(af[mf][ks], bfr[nf][ks],
                                                      acc[qm*4 + mf][qn*2 + nf], 0, 0, 0);
      __builtin_amdgcn_s_setprio(0);
      __builtin_amdgcn_s_barrier();
    }
  }

  // epilogue: fp32 direct stores (pad cols dropped)
#pragma unroll
  for (int nf = 0; nf < 4; ++nf){
    const int col = bn*256 + wn*64 + nf*16 + lm;
    if (col >= N) continue;
    const float bv = bias[col];
#pragma unroll
    for (int mf = 0; mf < 8; ++mf){
      const size_t rb = (size_t)(bm*256 + wm*128 + mf*16 + g*4);
#pragma unroll
      for (int r = 0; r < 4; ++r)
        C[(rb + r)*(size_t)N + col] = acc[mf][nf][r] + bv;
    }
  }
}

// ---------------- flash attention, static-max softmax + T14 stage split -----
// Loads for tile t+1 issued right after the first barrier (hidden under
// compute of t); ds_write of t+1's regs lands at next iteration top.
__global__ __launch_bounds__(256, 2) void k_attn(
    const UST* __restrict__ qa, const UST* __restrict__ ka,
    const UST* __restrict__ vt, const UST* __restrict__ outp_dummy,
    UST* __restrict__ outp)
{
  __shared__ __align__(16) UST lK[64][104];   // K tile [kv][d]
  __shared__ __align__(16) UST lV[96][72];    // V^T tile [d][kv]
  __shared__ __align__(16) UST lP[4][16][72]; // per-wave P [q][kv]
  const int bh = blockIdx.x, qt = blockIdx.y;
  const int t = threadIdx.x, wave = t >> 6, lane = t & 63;
  const int lm = lane & 15, g = lane >> 4;
  const int h = bh & 15, b = bh >> 4;

  bf16x8 qf[3];
  {
    const UST* qp = qa + ((size_t)bh*576 + qt*64 + wave*16 + lm)*96 + g*8;
#pragma unroll
    for (int ks = 0; ks < 3; ++ks) qf[ks] = __builtin_bit_cast(bf16x8, *(const us8*)(qp + ks*32));
  }
  f32x4 zero = {0.f,0.f,0.f,0.f};
  f32x4 acc[6];
#pragma unroll
  for (int i = 0; i < 6; ++i) acc[i] = zero;
  float psum[4];
#pragma unroll
  for (int r = 0; r < 4; ++r) psum[r] = 0.f;

  const UST* kbase = ka + (size_t)bh*576*96;
  const UST* vbase = vt + (size_t)bh*96*576;

  // T14 reg staging: K by all 256 thr (3x uint4), V by t<192 (4x uint4)
  const int rK = t >> 2, uK = t & 3;
  const int dV = t >> 1, hfV = t & 1;
  const UST* ksrc = kbase + (size_t)rK*96 + uK*24;
  const UST* vsrc = vbase + (size_t)dV*576 + hfV*32;
  uint4 kreg[3], vreg[4];
  auto loadrs = [&](int kvt){
#pragma unroll
    for (int i = 0; i < 3; ++i)
      kreg[i] = *(const uint4*)(ksrc + (size_t)kvt*6144 + i*8);
    if (t < 192){
#pragma unroll
      for (int i = 0; i < 4; ++i)
        vreg[i] = *(const uint4*)(vsrc + kvt*64 + i*8);
    }
  };
  loadrs(0);

  for (int kvt = 0; kvt < 9; ++kvt){
    // write staged regs -> LDS
#pragma unroll
    for (int i = 0; i < 3; ++i) *(uint4*)&lK[rK][uK*24 + i*8] = kreg[i];
    if (t < 192){
#pragma unroll
      for (int i = 0; i < 4; ++i) *(uint4*)&lV[dV][hfV*32 + i*8] = vreg[i];
    }
    __syncthreads();
    if (kvt + 1 < 9) loadrs(kvt + 1);   // issue next-tile loads under compute

    // QK^T -> sc[nf][r]: S[q = w*16 + 4g+r][kv = nf*16 + lm]
    f32x4 sc[4];
#pragma unroll
    for (int i = 0; i < 4; ++i) sc[i] = zero;
    __builtin_amdgcn_s_setprio(1);
#pragma unroll
    for (int ks = 0; ks < 3; ++ks){
#pragma unroll
      for (int nf = 0; nf < 4; ++nf){
        bf16x8 kf = __builtin_bit_cast(bf16x8, *(const us8*)&lK[nf*16 + lm][ks*32 + g*8]);
        sc[nf] = __builtin_amdgcn_mfma_f32_16x16x32_bf16(qf[ks], kf, sc[nf], 0, 0, 0);
      }
    }
    __builtin_amdgcn_s_setprio(0);

    // P = exp(S); per-lane partial row sums
#pragma unroll
    for (int r = 0; r < 4; ++r){
      float ls = 0.f;
#pragma unroll
      for (int nf = 0; nf < 4; ++nf){
        float p = __expf(sc[nf][r]);
        sc[nf][r] = p;
        ls += p;
      }
      psum[r] += ls;
    }

    // P -> LDS (wave-local), read back as A-frags
#pragma unroll
    for (int nf = 0; nf < 4; ++nf)
#pragma unroll
      for (int r = 0; r < 4; ++r)
        lP[wave][4*g + r][nf*16 + lm] = f2bf(sc[nf][r]);

    bf16x8 pa[2];
#pragma unroll
    for (int ks2 = 0; ks2 < 2; ++ks2)
      pa[ks2] = __builtin_bit_cast(bf16x8, *(const us8*)&lP[wave][lm][ks2*32 + g*8]);
    __builtin_amdgcn_s_setprio(1);
#pragma unroll
    for (int ks2 = 0; ks2 < 2; ++ks2)
#pragma unroll
      for (int df = 0; df < 6; ++df){
        bf16x8 vf = __builtin_bit_cast(bf16x8, *(const us8*)&lV[df*16 + lm][ks2*32 + g*8]);
        acc[df] = __builtin_amdgcn_mfma_f32_16x16x32_bf16(pa[ks2], vf, acc[df], 0, 0, 0);
      }
    __builtin_amdgcn_s_setprio(0);
    __syncthreads();
  }

  // single final cross-lane sum reduce
#pragma unroll
  for (int m = 1; m <= 8; m <<= 1)
#pragma unroll
    for (int r = 0; r < 4; ++r) psum[r] += __shfl_xor(psum[r], m, 64);
  float inv[4];
#pragma unroll
  for (int r = 0; r < 4; ++r) inv[r] = 1.f / psum[r];

  const size_t rowt = (size_t)b*576 + qt*64 + wave*16;
#pragma unroll
  for (int df = 0; df < 6; ++df){
    int d = df*16 + lm;
    if (d < 88){
#pragma unroll
      for (int r = 0; r < 4; ++r)
        outp[(rowt + 4*g + r)*1408 + h*88 + d] = f2bf(acc[df][r] * inv[r]);
    }
  }
}

// ---------------- launch ----------------------------------------------------
extern "C" void kernel_launch(void* const* d_in, const int* in_sizes, int n_in,
                              void* d_out, int out_size, void* d_ws, size_t ws_size,
                              hipStream_t stream)
{
  (void)in_sizes; (void)n_in; (void)out_size; (void)ws_size;
  const float* hs   = (const float*)d_in[0];
  const float* wqkv = (const float*)d_in[1];
  const float* bqkv = (const float*)d_in[2];
  const float* wo   = (const float*)d_in[3];
  const float* bo   = (const float*)d_in[4];
  float* out = (float*)d_out;

  char* w = (char*)d_ws;                       // needs ~127.4 MiB
  UST* A_bf   = (UST*)(w);                     // 25,952,256  (hidden bf16; reused as attn out)
  UST* Bt1    = (UST*)(w + 25952256);          // 11,894,784  (w_qkv^T bf16, 4224 rows)
  UST* Bt2    = (UST*)(w + 37847040);          //  4,325,376  (w_o^T bf16, padded 1536 rows)
  UST* qa     = (UST*)(w + 42172416);          // 28,311,552
  UST* ka     = (UST*)(w + 70483968);          // 28,311,552
  UST* vt     = (UST*)(w + 98795520);          // 28,311,552
  float* cs2  = (float*)(w + 127107072);       //    202,752

  k_tables<<<576, 64, 0, stream>>>(cs2);
  k_zero<<<576, 256, 0, stream>>>(qa, ka, vt);
  k_cvt<<<12672, 256, 0, stream>>>(hs, A_bf, 3244032);
  k_cvt_t<<<dim3(22, 66), 256, 0, stream>>>(wqkv, Bt1, 1408, 4224);
  k_cvt_t<<<dim3(22, 24), 256, 0, stream>>>(wo, Bt2, 1408, 1408);
  k_gemmqkv<<<dim3(72, 33), 256, 0, stream>>>(A_bf, Bt1, bqkv, 9216, 4224, 1408,
                                              qa, ka, vt, cs2);
  k_attn<<<dim3(256, 9), 256, 0, stream>>>(qa, ka, vt, nullptr, A_bf);
  k_gemm8p<<<dim3(36, 6), 512, 0, stream>>>(A_bf, Bt2, bo, out, 9216, 1408, 1408);
}

// Round 12
// 291.174 us; speedup vs baseline: 1.5821x; 1.5821x over previous
//
#include <hip/hip_runtime.h>
#include <hip/hip_bf16.h>

// Llama4 Vision Attention, MI355X bf16-MFMA pipeline.
// B=16 S=576 E=1408 H=16 D=88 (pad 96). fp32 in/out, bf16 internal compute.
// R12: revert to R10 composition (proven 293us). Fixes: epilogue sm[] swizzle
//      widened to row&15 (kills 1.6M bank conflicts); tables+zero fused.

typedef unsigned short UST;
typedef __attribute__((ext_vector_type(8))) __bf16 bf16x8;
typedef __attribute__((ext_vector_type(4))) float f32x4;
typedef __attribute__((ext_vector_type(8))) UST us8;
typedef __attribute__((ext_vector_type(4))) UST us4;

typedef __attribute__((address_space(3))) unsigned int lds_u32;
typedef const __attribute__((address_space(1))) unsigned int glob_u32;

static __device__ __forceinline__ UST f2bf(float f){
  unsigned int x = __builtin_bit_cast(unsigned int, f);
  x += 0x7fffu + ((x >> 16) & 1u);   // RN-even; inputs finite
  return (UST)(x >> 16);
}

// ------ prep: cs2 interleaved {cos,sin}[576][44] (f64 math) + zero pads -----
__global__ void k_prep(float* __restrict__ cs2,
                       UST* __restrict__ qa, UST* __restrict__ ka, UST* __restrict__ vt){
  const int x = blockIdx.x;                    // 0..575
  const int t = threadIdx.x;
  if (t < 44){
    int p = t;
    int tt = p % 22;
    double comp = (p < 22) ? (double)(x % 24 + 1) : (double)(x / 24 + 1);
    double a = comp * pow(10000.0, -(double)tt / 22.0);
    cs2[x*88 + 2*p]     = (float)cos(a);
    cs2[x*88 + 2*p + 1] = (float)sin(a);
  }
  int c = x*256 + t;                           // 0..147455 = 256bh * 576
  int bh = c / 576, s = c - bh*576;
  us8 z = {0,0,0,0,0,0,0,0};
  *(us8*)(qa + ((size_t)bh*576 + s)*96 + 88) = z;
  *(us8*)(ka + ((size_t)bh*576 + s)*96 + 88) = z;
  *(us8*)(vt + (size_t)bh*55296 + 50688 + s*8) = z;   // rows 88..95 of [96][576]
}

// ---------------- fp32 -> bf16 cast (vectorized) ----------------------------
__global__ void k_cvt(const float* __restrict__ in, UST* __restrict__ out, int n4){
  int i = blockIdx.x * 256 + threadIdx.x;
  if (i >= n4) return;
  float4 v = ((const float4*)in)[i];
  us4 o; o[0]=f2bf(v.x); o[1]=f2bf(v.y); o[2]=f2bf(v.z); o[3]=f2bf(v.w);
  *(us4*)(out + 4*(size_t)i) = o;
}

// ---------------- fp32 [K][N] -> bf16 [N][K] transpose-convert --------------
__global__ void k_cvt_t(const float* __restrict__ W, UST* __restrict__ Bt, int K, int N){
  __shared__ __align__(16) UST tl[64][70];  // odd dword stride -> low conflict
  int kt = blockIdx.x, nt = blockIdx.y;
  int t = threadIdx.x;
  int k = t >> 2, u = t & 3;
  const float* src = W + (size_t)(kt*64 + k)*N + nt*64 + u*16;
#pragma unroll
  for (int i = 0; i < 4; ++i){
    float4 v = *(const float4*)(src + 4*i);
    UST* d = &tl[k][u*16 + 4*i];
    d[0]=f2bf(v.x); d[1]=f2bf(v.y); d[2]=f2bf(v.z); d[3]=f2bf(v.w);
  }
  __syncthreads();
  int n = t >> 2;
  UST* dst = Bt + (size_t)(nt*64 + n)*K + kt*64 + u*16;
#pragma unroll
  for (int i = 0; i < 2; ++i){
    us8 o;
#pragma unroll
    for (int j = 0; j < 8; ++j) o[j] = tl[u*16 + 8*i + j][n];
    *(us8*)(dst + 8*i) = o;
  }
}

// ---------------- bf16 GEMM (round-2 proven body) + fused epilogues ---------
// EPI 0: fp32 out, stride N (final projection), direct stores.
// EPI 3: QKV fused. After mainloop, acc+bias staged to LDS (aliased with
//   lA/lB, chunk-XOR swizzle row&15 both sides), coalesced us8 stores:
//   q/k: 8-col chunk = 4 rope pairs in-register; v: 8-row run -> vt.
template<int EPI>
__global__ __launch_bounds__(256, 2) void k_gemm(
    const UST* __restrict__ A, const UST* __restrict__ Bt,
    const float* __restrict__ bias, void* __restrict__ Cout,
    int M, int N, int K,
    UST* __restrict__ qa, UST* __restrict__ ka, UST* __restrict__ vt,
    const float* __restrict__ cs2)
{
  __shared__ __align__(16) char SMEM[65536];
  UST (*lA)[128][64] = reinterpret_cast<UST(*)[128][64]>(SMEM);          // [2]
  UST (*lB)[128][64] = reinterpret_cast<UST(*)[128][64]>(SMEM + 32768);  // [2]
  float* sm = reinterpret_cast<float*>(SMEM);                            // [128][128]

  const int t = threadIdx.x;
  const int bm = blockIdx.x, bn = blockIdx.y;
  const int wave = t >> 6, lane = t & 63;
  const int lm = lane & 15, g = lane >> 4;
  const int wr = (wave >> 1) << 6, wc = (wave & 1) << 6;
  const int lrow = lane >> 3;                       // 0..7 within 8-row chunk
  const int lcol = (((lane & 7) ^ lrow) << 3);      // pre-swizzled source col
  const UST* Ag = A  + (size_t)(bm*128 + wave*32 + lrow)*K + lcol;
  const UST* Bg = Bt + (size_t)(bn*128 + wave*32 + lrow)*K + lcol;

  f32x4 zero = {0.f,0.f,0.f,0.f};
  f32x4 acc[4][4];
#pragma unroll
  for (int i=0;i<4;++i)
#pragma unroll
    for (int j=0;j<4;++j) acc[i][j] = zero;

  const int nkt = K >> 6;
  auto stage = [&](int kt, int buf){
#pragma unroll
    for (int c = 0; c < 4; ++c){
      __builtin_amdgcn_global_load_lds((glob_u32*)(Ag + (size_t)kt*64 + (size_t)(8*c)*K),
                                       (lds_u32*)(&lA[buf][wave*32 + 8*c][0]), 16, 0, 0);
      __builtin_amdgcn_global_load_lds((glob_u32*)(Bg + (size_t)kt*64 + (size_t)(8*c)*K),
                                       (lds_u32*)(&lB[buf][wave*32 + 8*c][0]), 16, 0, 0);
    }
  };

  stage(0, 0);
  __syncthreads();
  const int swz = (lm & 7) << 3;

  for (int kt = 0; kt < nkt; ++kt){
    const int cur = kt & 1;
    if (kt + 1 < nkt) stage(kt + 1, cur ^ 1);
#pragma unroll
    for (int ks = 0; ks < 2; ++ks){
      bf16x8 af[4], bfv[4];
      const int cb = (ks*32 + g*8) ^ swz;
#pragma unroll
      for (int mf = 0; mf < 4; ++mf)
        af[mf] = __builtin_bit_cast(bf16x8, *(const us8*)&lA[cur][wr + mf*16 + lm][cb]);
#pragma unroll
      for (int nf = 0; nf < 4; ++nf)
        bfv[nf] = __builtin_bit_cast(bf16x8, *(const us8*)&lB[cur][wc + nf*16 + lm][cb]);
#pragma unroll
      for (int mf = 0; mf < 4; ++mf)
#pragma unroll
        for (int nf = 0; nf < 4; ++nf)
          acc[mf][nf] = __builtin_amdgcn_mfma_f32_16x16x32_bf16(af[mf], bfv[nf], acc[mf][nf], 0, 0, 0);
    }
    __syncthreads();   // drains vmcnt -> next buffer ready; protects buffer reuse
  }

  if (EPI == 0){
#pragma unroll
    for (int nf = 0; nf < 4; ++nf){
      const int col = bn*128 + wc + nf*16 + lm;
      const float bv = bias[col];
#pragma unroll
      for (int mf = 0; mf < 4; ++mf){
        const size_t rb = (size_t)(bm*128 + wr + mf*16 + g*4);
#pragma unroll
        for (int r = 0; r < 4; ++r)
          ((float*)Cout)[(rb + r)*(size_t)N + col] = acc[mf][nf][r] + bv;
      }
    }
  } else {
    // ---- stage acc+bias into swizzled sm[128][128] (lA/lB dead) ----
#pragma unroll
    for (int nf = 0; nf < 4; ++nf){
      const int col = wc + nf*16 + lm;
      const float bv = bias[bn*128 + col];
#pragma unroll
      for (int mf = 0; mf < 4; ++mf){
#pragma unroll
        for (int r = 0; r < 4; ++r){
          const int row = wr + mf*16 + g*4 + r;
          const int colS = (((col >> 3) ^ (row & 15)) << 3) | (col & 7);
          sm[row*128 + colS] = acc[mf][nf][r] + bv;
        }
      }
    }
    __syncthreads();

    const int j = bn / 11;               // 0 q, 1 k, 2 v (uniform per block)
    const int bnr = bn - j*11;
    if (j == 2){
      // v: thread reads an 8-row column run -> 16B store to vt[bh][dv][s0..s0+7]
#pragma unroll
      for (int i = 0; i < 8; ++i){
        const int idx = t + 256*i;
        const int col = idx & 127, rch = idx >> 7;   // rch 0..15
        const int cv = bnr*128 + col;
        const int h = cv / 88, dv = cv - h*88;
        const int s0g = bm*128 + rch*8;              // 8-run never crosses b (576%8==0)
        const int b2 = s0g / 576, sl = s0g - b2*576;
        us8 o;
#pragma unroll
        for (int k = 0; k < 8; ++k){
          const int row = rch*8 + k;
          const int colS = (((col >> 3) ^ (row & 15)) << 3) | (col & 7);
          o[k] = f2bf(sm[row*128 + colS]);
        }
        *(us8*)(vt + ((size_t)(b2*16 + h)*96 + dv)*576 + sl) = o;
      }
    } else {
      // q/k: thread reads one row's 8-col chunk = 4 rope pairs; 16B store
      UST* outp = j ? ka : qa;
      const float sc = j ? 1.0f : 0.10660035817780521f;   // 88^-0.5 into q
#pragma unroll
      for (int i = 0; i < 8; ++i){
        const int idx = t + 256*i;
        const int ch = idx & 15, rr = idx >> 4;      // rr 0..127
        const int cv = bnr*128 + ch*8;               // aligned-8: same h for all 8
        const int h = cv / 88, d0 = cv - h*88;
        const int rb = bm*128 + rr;
        const int b2 = rb / 576, s = rb - b2*576;
        const float* src = &sm[rr*128 + ((ch ^ (rr & 15)) << 3)];
        float x[8];
#pragma unroll
        for (int k = 0; k < 8; ++k) x[k] = src[k];
        const float* tb = cs2 + s*88 + d0;           // {c,s} pairs, 32B-aligned
        float4 q0 = *(const float4*)(tb);
        float4 q1 = *(const float4*)(tb + 4);
        float cc[4]  = {q0.x, q0.z, q1.x, q1.z};
        float ssv[4] = {q0.y, q0.w, q1.y, q1.w};
        us8 o;
#pragma unroll
        for (int p = 0; p < 4; ++p){
          float o0 = (x[2*p]*cc[p]  - x[2*p+1]*ssv[p]) * sc;
          float o1 = (x[2*p]*ssv[p] + x[2*p+1]*cc[p])  * sc;
          o[2*p] = f2bf(o0); o[2*p+1] = f2bf(o1);
        }
        *(us8*)(outp + ((size_t)(b2*16 + h)*576 + s)*96 + d0) = o;
      }
    }
  }
}

// ---------------- flash attention, static-max softmax (R9/R10 proven) -------
__global__ __launch_bounds__(256, 2) void k_attn(
    const UST* __restrict__ qa, const UST* __restrict__ ka,
    const UST* __restrict__ vt, UST* __restrict__ outp)
{
  __shared__ __align__(16) UST lK[64][104];   // K tile [kv][d]
  __shared__ __align__(16) UST lV[96][72];    // V^T tile [d][kv]
  __shared__ __align__(16) UST lP[4][16][72]; // per-wave P [q][kv]
  const int bh = blockIdx.x, qt = blockIdx.y;
  const int t = threadIdx.x, wave = t >> 6, lane = t & 63;
  const int lm = lane & 15, g = lane >> 4;
  const int h = bh & 15, b = bh >> 4;

  bf16x8 qf[3];
  {
    const UST* qp = qa + ((size_t)bh*576 + qt*64 + wave*16 + lm)*96 + g*8;
#pragma unroll
    for (int ks = 0; ks < 3; ++ks) qf[ks] = __builtin_bit_cast(bf16x8, *(const us8*)(qp + ks*32));
  }
  f32x4 zero = {0.f,0.f,0.f,0.f};
  f32x4 acc[6];
#pragma unroll
  for (int i = 0; i < 6; ++i) acc[i] = zero;
  float psum[4];
#pragma unroll
  for (int r = 0; r < 4; ++r) psum[r] = 0.f;

  const UST* kbase = ka + (size_t)bh*576*96;
  const UST* vbase = vt + (size_t)bh*96*576;

  for (int kvt = 0; kvt < 9; ++kvt){
    { // stage K [64][96]
      int r = t >> 2, u = t & 3;
      const UST* src = kbase + (size_t)(kvt*64 + r)*96 + u*24;
#pragma unroll
      for (int i = 0; i < 3; ++i)
        *(uint4*)&lK[r][u*24 + i*8] = *(const uint4*)(src + i*8);
    }
    if (t < 192){ // stage V^T [96][64]
      int d = t >> 1, hf = t & 1;
      const UST* src = vbase + (size_t)d*576 + kvt*64 + hf*32;
#pragma unroll
      for (int i = 0; i < 4; ++i)
        *(uint4*)&lV[d][hf*32 + i*8] = *(const uint4*)(src + i*8);
    }
    __syncthreads();

    // QK^T -> sc[nf][r]: S[q = w*16 + 4g+r][kv = nf*16 + lm]
    f32x4 sc[4];
#pragma unroll
    for (int i = 0; i < 4; ++i) sc[i] = zero;
    __builtin_amdgcn_s_setprio(1);
#pragma unroll
    for (int ks = 0; ks < 3; ++ks){
#pragma unroll
      for (int nf = 0; nf < 4; ++nf){
        bf16x8 kf = __builtin_bit_cast(bf16x8, *(const us8*)&lK[nf*16 + lm][ks*32 + g*8]);
        sc[nf] = __builtin_amdgcn_mfma_f32_16x16x32_bf16(qf[ks], kf, sc[nf], 0, 0, 0);
      }
    }
    __builtin_amdgcn_s_setprio(0);

    // P = exp(S); per-lane partial row sums (no reduce, no rescale)
#pragma unroll
    for (int r = 0; r < 4; ++r){
      float ls = 0.f;
#pragma unroll
      for (int nf = 0; nf < 4; ++nf){
        float p = __expf(sc[nf][r]);
        sc[nf][r] = p;
        ls += p;
      }
      psum[r] += ls;
    }

    // P -> LDS (wave-local), read back as A-frags
#pragma unroll
    for (int nf = 0; nf < 4; ++nf)
#pragma unroll
      for (int r = 0; r < 4; ++r)
        lP[wave][4*g + r][nf*16 + lm] = f2bf(sc[nf][r]);

    bf16x8 pa[2];
#pragma unroll
    for (int ks2 = 0; ks2 < 2; ++ks2)
      pa[ks2] = __builtin_bit_cast(bf16x8, *(const us8*)&lP[wave][lm][ks2*32 + g*8]);
    __builtin_amdgcn_s_setprio(1);
#pragma unroll
    for (int ks2 = 0; ks2 < 2; ++ks2)
#pragma unroll
      for (int df = 0; df < 6; ++df){
        bf16x8 vf = __builtin_bit_cast(bf16x8, *(const us8*)&lV[df*16 + lm][ks2*32 + g*8]);
        acc[df] = __builtin_amdgcn_mfma_f32_16x16x32_bf16(pa[ks2], vf, acc[df], 0, 0, 0);
      }
    __builtin_amdgcn_s_setprio(0);
    __syncthreads();
  }

  // single final cross-lane sum reduce (over the 16 lm lanes of each g-group)
#pragma unroll
  for (int m = 1; m <= 8; m <<= 1)
#pragma unroll
    for (int r = 0; r < 4; ++r) psum[r] += __shfl_xor(psum[r], m, 64);
  float inv[4];
#pragma unroll
  for (int r = 0; r < 4; ++r) inv[r] = 1.f / psum[r];

  const size_t rowt = (size_t)b*576 + qt*64 + wave*16;
#pragma unroll
  for (int df = 0; df < 6; ++df){
    int d = df*16 + lm;
    if (d < 88){
#pragma unroll
      for (int r = 0; r < 4; ++r)
        outp[(rowt + 4*g + r)*1408 + h*88 + d] = f2bf(acc[df][r] * inv[r]);
    }
  }
}

// ---------------- launch ----------------------------------------------------
extern "C" void kernel_launch(void* const* d_in, const int* in_sizes, int n_in,
                              void* d_out, int out_size, void* d_ws, size_t ws_size,
                              hipStream_t stream)
{
  (void)in_sizes; (void)n_in; (void)out_size; (void)ws_size;
  const float* hs   = (const float*)d_in[0];
  const float* wqkv = (const float*)d_in[1];
  const float* bqkv = (const float*)d_in[2];
  const float* wo   = (const float*)d_in[3];
  const float* bo   = (const float*)d_in[4];
  float* out = (float*)d_out;

  char* w = (char*)d_ws;                       // needs ~127 MiB
  UST* A_bf   = (UST*)(w);                     // 25,952,256  (hidden bf16; reused as attn out)
  UST* Bt1    = (UST*)(w + 25952256);          // 11,894,784  (w_qkv^T bf16)
  UST* Bt2    = (UST*)(w + 37847040);          //  3,964,928  (w_o^T bf16)
  UST* qa     = (UST*)(w + 41811968);          // 28,311,552
  UST* ka     = (UST*)(w + 70123520);          // 28,311,552
  UST* vt     = (UST*)(w + 98435072);          // 28,311,552
  float* cs2  = (float*)(w + 126746624);       //    202,752

  k_prep<<<576, 256, 0, stream>>>(cs2, qa, ka, vt);
  k_cvt<<<12672, 256, 0, stream>>>(hs, A_bf, 3244032);
  k_cvt_t<<<dim3(22, 66), 256, 0, stream>>>(wqkv, Bt1, 1408, 4224);
  k_cvt_t<<<dim3(22, 22), 256, 0, stream>>>(wo, Bt2, 1408, 1408);
  k_gemm<3><<<dim3(72, 33), 256, 0, stream>>>(A_bf, Bt1, bqkv, nullptr, 9216, 4224, 1408,
                                              qa, ka, vt, cs2);
  k_attn<<<dim3(256, 9), 256, 0, stream>>>(qa, ka, vt, A_bf);
  k_gemm<0><<<dim3(72, 11), 256, 0, stream>>>(A_bf, Bt2, bo, out, 9216, 1408, 1408,
                                              nullptr, nullptr, nullptr, nullptr);
}

// Round 13
// 283.438 us; speedup vs baseline: 1.6253x; 1.0273x over previous
//
#include <hip/hip_runtime.h>
#include <hip/hip_bf16.h>

// Llama4 Vision Attention, MI355X bf16-MFMA pipeline.
// B=16 S=576 E=1408 H=16 D=88 (pad 96). fp32 in/out, bf16 internal compute.
// R13: attn KVBLK=96 (6 iters, 52KB LDS, 3 blocks/CU); epilogue swizzle fixed
//      to bank-relevant bits (sw2 = (row^(row>>2))&3); prep folded into cvt;
//      both weight transposes in one launch.

typedef unsigned short UST;
typedef __attribute__((ext_vector_type(8))) __bf16 bf16x8;
typedef __attribute__((ext_vector_type(4))) float f32x4;
typedef __attribute__((ext_vector_type(8))) UST us8;
typedef __attribute__((ext_vector_type(4))) UST us4;

typedef __attribute__((address_space(3))) unsigned int lds_u32;
typedef const __attribute__((address_space(1))) unsigned int glob_u32;

static __device__ __forceinline__ UST f2bf(float f){
  unsigned int x = __builtin_bit_cast(unsigned int, f);
  x += 0x7fffu + ((x >> 16) & 1u);   // RN-even; inputs finite
  return (UST)(x >> 16);
}

// ---------------- fp32 -> bf16 cast; blocks<576 also do table+pad prep ------
__global__ void k_cvt(const float* __restrict__ in, UST* __restrict__ out, int n4,
                      float* __restrict__ cs2,
                      UST* __restrict__ qa, UST* __restrict__ ka, UST* __restrict__ vt){
  int i = blockIdx.x * 256 + threadIdx.x;
  if (i < n4){
    float4 v = ((const float4*)in)[i];
    us4 o; o[0]=f2bf(v.x); o[1]=f2bf(v.y); o[2]=f2bf(v.z); o[3]=f2bf(v.w);
    *(us4*)(out + 4*(size_t)i) = o;
  }
  if (blockIdx.x < 576){
    const int x = blockIdx.x, t = threadIdx.x;
    if (t < 44){
      int p = t;
      int tt = p % 22;
      double comp = (p < 22) ? (double)(x % 24 + 1) : (double)(x / 24 + 1);
      double a = comp * pow(10000.0, -(double)tt / 22.0);
      cs2[x*88 + 2*p]     = (float)cos(a);
      cs2[x*88 + 2*p + 1] = (float)sin(a);
    }
    int c = x*256 + t;                           // 0..147455 = 256bh * 576
    int bh = c / 576, s = c - bh*576;
    us8 z = {0,0,0,0,0,0,0,0};
    *(us8*)(qa + ((size_t)bh*576 + s)*96 + 88) = z;
    *(us8*)(ka + ((size_t)bh*576 + s)*96 + 88) = z;
    *(us8*)(vt + (size_t)bh*55296 + 50688 + s*8) = z;   // rows 88..95 of [96][576]
  }
}

// -------- fp32 [K][N] -> bf16 [N][K] transpose-convert, both weights --------
// grid (22, 88): nt<66 -> w_qkv (N=4224) -> Bt1; else w_o (N=1408) -> Bt2.
__global__ void k_cvt_t(const float* __restrict__ Wq, const float* __restrict__ Wo,
                        UST* __restrict__ Bt1, UST* __restrict__ Bt2){
  __shared__ __align__(16) UST tl[64][70];  // odd dword stride -> low conflict
  const int K = 1408;
  int kt = blockIdx.x, nt = blockIdx.y;
  const float* W; UST* Bt; int N, ntl;
  if (nt < 66){ W = Wq; Bt = Bt1; N = 4224; ntl = nt; }
  else        { W = Wo; Bt = Bt2; N = 1408; ntl = nt - 66; }
  int t = threadIdx.x;
  int k = t >> 2, u = t & 3;
  const float* src = W + (size_t)(kt*64 + k)*N + ntl*64 + u*16;
#pragma unroll
  for (int i = 0; i < 4; ++i){
    float4 v = *(const float4*)(src + 4*i);
    UST* d = &tl[k][u*16 + 4*i];
    d[0]=f2bf(v.x); d[1]=f2bf(v.y); d[2]=f2bf(v.z); d[3]=f2bf(v.w);
  }
  __syncthreads();
  int n = t >> 2;
  UST* dst = Bt + (size_t)(ntl*64 + n)*K + kt*64 + u*16;
#pragma unroll
  for (int i = 0; i < 2; ++i){
    us8 o;
#pragma unroll
    for (int j = 0; j < 8; ++j) o[j] = tl[u*16 + 8*i + j][n];
    *(us8*)(dst + 8*i) = o;
  }
}

// ---------------- bf16 GEMM (round-2 proven body) + fused epilogues ---------
// EPI 0: fp32 out, stride N (final projection), direct stores.
// EPI 3: QKV fused. acc+bias staged to LDS (aliased with lA/lB), swizzle
//   chunk ^= (row ^ (row>>2))&3 — the only bank-relevant bits — both sides.
template<int EPI>
__global__ __launch_bounds__(256, 2) void k_gemm(
    const UST* __restrict__ A, const UST* __restrict__ Bt,
    const float* __restrict__ bias, void* __restrict__ Cout,
    int M, int N, int K,
    UST* __restrict__ qa, UST* __restrict__ ka, UST* __restrict__ vt,
    const float* __restrict__ cs2)
{
  __shared__ __align__(16) char SMEM[65536];
  UST (*lA)[128][64] = reinterpret_cast<UST(*)[128][64]>(SMEM);          // [2]
  UST (*lB)[128][64] = reinterpret_cast<UST(*)[128][64]>(SMEM + 32768);  // [2]
  float* sm = reinterpret_cast<float*>(SMEM);                            // [128][128]

  const int t = threadIdx.x;
  const int bm = blockIdx.x, bn = blockIdx.y;
  const int wave = t >> 6, lane = t & 63;
  const int lm = lane & 15, g = lane >> 4;
  const int wr = (wave >> 1) << 6, wc = (wave & 1) << 6;
  const int lrow = lane >> 3;                       // 0..7 within 8-row chunk
  const int lcol = (((lane & 7) ^ lrow) << 3);      // pre-swizzled source col
  const UST* Ag = A  + (size_t)(bm*128 + wave*32 + lrow)*K + lcol;
  const UST* Bg = Bt + (size_t)(bn*128 + wave*32 + lrow)*K + lcol;

  f32x4 zero = {0.f,0.f,0.f,0.f};
  f32x4 acc[4][4];
#pragma unroll
  for (int i=0;i<4;++i)
#pragma unroll
    for (int j=0;j<4;++j) acc[i][j] = zero;

  const int nkt = K >> 6;
  auto stage = [&](int kt, int buf){
#pragma unroll
    for (int c = 0; c < 4; ++c){
      __builtin_amdgcn_global_load_lds((glob_u32*)(Ag + (size_t)kt*64 + (size_t)(8*c)*K),
                                       (lds_u32*)(&lA[buf][wave*32 + 8*c][0]), 16, 0, 0);
      __builtin_amdgcn_global_load_lds((glob_u32*)(Bg + (size_t)kt*64 + (size_t)(8*c)*K),
                                       (lds_u32*)(&lB[buf][wave*32 + 8*c][0]), 16, 0, 0);
    }
  };

  stage(0, 0);
  __syncthreads();
  const int swz = (lm & 7) << 3;

  for (int kt = 0; kt < nkt; ++kt){
    const int cur = kt & 1;
    if (kt + 1 < nkt) stage(kt + 1, cur ^ 1);
#pragma unroll
    for (int ks = 0; ks < 2; ++ks){
      bf16x8 af[4], bfv[4];
      const int cb = (ks*32 + g*8) ^ swz;
#pragma unroll
      for (int mf = 0; mf < 4; ++mf)
        af[mf] = __builtin_bit_cast(bf16x8, *(const us8*)&lA[cur][wr + mf*16 + lm][cb]);
#pragma unroll
      for (int nf = 0; nf < 4; ++nf)
        bfv[nf] = __builtin_bit_cast(bf16x8, *(const us8*)&lB[cur][wc + nf*16 + lm][cb]);
#pragma unroll
      for (int mf = 0; mf < 4; ++mf)
#pragma unroll
        for (int nf = 0; nf < 4; ++nf)
          acc[mf][nf] = __builtin_amdgcn_mfma_f32_16x16x32_bf16(af[mf], bfv[nf], acc[mf][nf], 0, 0, 0);
    }
    __syncthreads();   // drains vmcnt -> next buffer ready; protects buffer reuse
  }

  if (EPI == 0){
#pragma unroll
    for (int nf = 0; nf < 4; ++nf){
      const int col = bn*128 + wc + nf*16 + lm;
      const float bv = bias[col];
#pragma unroll
      for (int mf = 0; mf < 4; ++mf){
        const size_t rb = (size_t)(bm*128 + wr + mf*16 + g*4);
#pragma unroll
        for (int r = 0; r < 4; ++r)
          ((float*)Cout)[(rb + r)*(size_t)N + col] = acc[mf][nf][r] + bv;
      }
    }
  } else {
    // ---- stage acc+bias into swizzled sm[128][128] (lA/lB dead) ----
#pragma unroll
    for (int nf = 0; nf < 4; ++nf){
      const int col = wc + nf*16 + lm;
      const float bv = bias[bn*128 + col];
#pragma unroll
      for (int mf = 0; mf < 4; ++mf){
#pragma unroll
        for (int r = 0; r < 4; ++r){
          const int row = wr + mf*16 + g*4 + r;
          const int sw2 = (row ^ (row >> 2)) & 3;
          const int colS = (((col >> 3) ^ sw2) << 3) | (col & 7);
          sm[row*128 + colS] = acc[mf][nf][r] + bv;
        }
      }
    }
    __syncthreads();

    const int j = bn / 11;               // 0 q, 1 k, 2 v (uniform per block)
    const int bnr = bn - j*11;
    if (j == 2){
      // v: thread reads an 8-row column run -> 16B store to vt[bh][dv][s0..s0+7]
#pragma unroll
      for (int i = 0; i < 8; ++i){
        const int idx = t + 256*i;
        const int col = idx & 127, rch = idx >> 7;   // rch 0..15
        const int cv = bnr*128 + col;
        const int h = cv / 88, dv = cv - h*88;
        const int s0g = bm*128 + rch*8;              // 8-run never crosses b (576%8==0)
        const int b2 = s0g / 576, sl = s0g - b2*576;
        us8 o;
#pragma unroll
        for (int k = 0; k < 8; ++k){
          const int row = rch*8 + k;
          const int sw2 = (row ^ (row >> 2)) & 3;
          const int colS = (((col >> 3) ^ sw2) << 3) | (col & 7);
          o[k] = f2bf(sm[row*128 + colS]);
        }
        *(us8*)(vt + ((size_t)(b2*16 + h)*96 + dv)*576 + sl) = o;
      }
    } else {
      // q/k: thread reads one row's 8-col chunk = 4 rope pairs; 16B store
      UST* outp = j ? ka : qa;
      const float sc = j ? 1.0f : 0.10660035817780521f;   // 88^-0.5 into q
#pragma unroll
      for (int i = 0; i < 8; ++i){
        const int idx = t + 256*i;
        const int ch = idx & 15, rr = idx >> 4;      // rr 0..127
        const int cv = bnr*128 + ch*8;               // aligned-8: same h for all 8
        const int h = cv / 88, d0 = cv - h*88;
        const int rb = bm*128 + rr;
        const int b2 = rb / 576, s = rb - b2*576;
        const int sw2 = (rr ^ (rr >> 2)) & 3;
        const float* src = &sm[rr*128 + ((ch ^ sw2) << 3)];
        float x[8];
#pragma unroll
        for (int k = 0; k < 8; ++k) x[k] = src[k];
        const float* tb = cs2 + s*88 + d0;           // {c,s} pairs, 32B-aligned
        float4 q0 = *(const float4*)(tb);
        float4 q1 = *(const float4*)(tb + 4);
        float cc[4]  = {q0.x, q0.z, q1.x, q1.z};
        float ssv[4] = {q0.y, q0.w, q1.y, q1.w};
        us8 o;
#pragma unroll
        for (int p = 0; p < 4; ++p){
          float o0 = (x[2*p]*cc[p]  - x[2*p+1]*ssv[p]) * sc;
          float o1 = (x[2*p]*ssv[p] + x[2*p+1]*cc[p])  * sc;
          o[2*p] = f2bf(o0); o[2*p+1] = f2bf(o1);
        }
        *(us8*)(outp + ((size_t)(b2*16 + h)*576 + s)*96 + d0) = o;
      }
    }
  }
}

// ---------------- flash attention, static-max softmax, KVBLK=96 -------------
// 6 iterations (576 = 6*96, no tail), 52KB LDS -> 3 blocks/CU, barriers 12.
__global__ __launch_bounds__(256, 2) void k_attn(
    const UST* __restrict__ qa, const UST* __restrict__ ka,
    const UST* __restrict__ vt, UST* __restrict__ outp)
{
  __shared__ __align__(16) UST lK[96][104];   // K tile [kv][d]
  __shared__ __align__(16) UST lV[96][104];   // V^T tile [d][kv]
  __shared__ __align__(16) UST lP[4][16][104];// per-wave P [q][kv]
  const int bh = blockIdx.x, qt = blockIdx.y;
  const int t = threadIdx.x, wave = t >> 6, lane = t & 63;
  const int lm = lane & 15, g = lane >> 4;
  const int h = bh & 15, b = bh >> 4;

  bf16x8 qf[3];
  {
    const UST* qp = qa + ((size_t)bh*576 + qt*64 + wave*16 + lm)*96 + g*8;
#pragma unroll
    for (int ks = 0; ks < 3; ++ks) qf[ks] = __builtin_bit_cast(bf16x8, *(const us8*)(qp + ks*32));
  }
  f32x4 zero = {0.f,0.f,0.f,0.f};
  f32x4 acc[6];
#pragma unroll
  for (int i = 0; i < 6; ++i) acc[i] = zero;
  float psum[4];
#pragma unroll
  for (int r = 0; r < 4; ++r) psum[r] = 0.f;

  const UST* kbase = ka + (size_t)bh*576*96;
  const UST* vbase = vt + (size_t)bh*96*576;

  for (int kvt = 0; kvt < 6; ++kvt){
    if (t < 192){  // stage K [96][96] and V^T [96][96]; 2 thr/row, 48 cols each
      const int r = t >> 1, half = t & 1;
      const UST* srcK = kbase + (size_t)(kvt*96 + r)*96 + half*48;
      const UST* srcV = vbase + (size_t)r*576 + kvt*96 + half*48;
#pragma unroll
      for (int i2 = 0; i2 < 6; ++i2){
        *(uint4*)&lK[r][half*48 + i2*8] = *(const uint4*)(srcK + i2*8);
        *(uint4*)&lV[r][half*48 + i2*8] = *(const uint4*)(srcV + i2*8);
      }
    }
    __syncthreads();

    // QK^T -> sc[nf][r]: S[q = w*16 + 4g+r][kv = nf*16 + lm]
    f32x4 sc[6];
#pragma unroll
    for (int i = 0; i < 6; ++i) sc[i] = zero;
    __builtin_amdgcn_s_setprio(1);
#pragma unroll
    for (int ks = 0; ks < 3; ++ks){
#pragma unroll
      for (int nf = 0; nf < 6; ++nf){
        bf16x8 kf = __builtin_bit_cast(bf16x8, *(const us8*)&lK[nf*16 + lm][ks*32 + g*8]);
        sc[nf] = __builtin_amdgcn_mfma_f32_16x16x32_bf16(qf[ks], kf, sc[nf], 0, 0, 0);
      }
    }
    __builtin_amdgcn_s_setprio(0);

    // P = exp(S); per-lane partial row sums (no reduce, no rescale)
#pragma unroll
    for (int r = 0; r < 4; ++r){
      float ls = 0.f;
#pragma unroll
      for (int nf = 0; nf < 6; ++nf){
        float p = __expf(sc[nf][r]);
        sc[nf][r] = p;
        ls += p;
      }
      psum[r] += ls;
    }

    // P -> LDS (wave-local), read back as A-frags
#pragma unroll
    for (int nf = 0; nf < 6; ++nf)
#pragma unroll
      for (int r = 0; r < 4; ++r)
        lP[wave][4*g + r][nf*16 + lm] = f2bf(sc[nf][r]);

    bf16x8 pa[3];
#pragma unroll
    for (int ks2 = 0; ks2 < 3; ++ks2)
      pa[ks2] = __builtin_bit_cast(bf16x8, *(const us8*)&lP[wave][lm][ks2*32 + g*8]);
    __builtin_amdgcn_s_setprio(1);
#pragma unroll
    for (int ks2 = 0; ks2 < 3; ++ks2)
#pragma unroll
      for (int df = 0; df < 6; ++df){
        bf16x8 vf = __builtin_bit_cast(bf16x8, *(const us8*)&lV[df*16 + lm][ks2*32 + g*8]);
        acc[df] = __builtin_amdgcn_mfma_f32_16x16x32_bf16(pa[ks2], vf, acc[df], 0, 0, 0);
      }
    __builtin_amdgcn_s_setprio(0);
    __syncthreads();
  }

  // single final cross-lane sum reduce (over the 16 lm lanes of each g-group)
#pragma unroll
  for (int m = 1; m <= 8; m <<= 1)
#pragma unroll
    for (int r = 0; r < 4; ++r) psum[r] += __shfl_xor(psum[r], m, 64);
  float inv[4];
#pragma unroll
  for (int r = 0; r < 4; ++r) inv[r] = 1.f / psum[r];

  const size_t rowt = (size_t)b*576 + qt*64 + wave*16;
#pragma unroll
  for (int df = 0; df < 6; ++df){
    int d = df*16 + lm;
    if (d < 88){
#pragma unroll
      for (int r = 0; r < 4; ++r)
        outp[(rowt + 4*g + r)*1408 + h*88 + d] = f2bf(acc[df][r] * inv[r]);
    }
  }
}

// ---------------- launch ----------------------------------------------------
extern "C" void kernel_launch(void* const* d_in, const int* in_sizes, int n_in,
                              void* d_out, int out_size, void* d_ws, size_t ws_size,
                              hipStream_t stream)
{
  (void)in_sizes; (void)n_in; (void)out_size; (void)ws_size;
  const float* hs   = (const float*)d_in[0];
  const float* wqkv = (const float*)d_in[1];
  const float* bqkv = (const float*)d_in[2];
  const float* wo   = (const float*)d_in[3];
  const float* bo   = (const float*)d_in[4];
  float* out = (float*)d_out;

  char* w = (char*)d_ws;                       // needs ~127 MiB
  UST* A_bf   = (UST*)(w);                     // 25,952,256  (hidden bf16; reused as attn out)
  UST* Bt1    = (UST*)(w + 25952256);          // 11,894,784  (w_qkv^T bf16)
  UST* Bt2    = (UST*)(w + 37847040);          //  3,964,928  (w_o^T bf16)
  UST* qa     = (UST*)(w + 41811968);          // 28,311,552
  UST* ka     = (UST*)(w + 70123520);          // 28,311,552
  UST* vt     = (UST*)(w + 98435072);          // 28,311,552
  float* cs2  = (float*)(w + 126746624);       //    202,752

  k_cvt<<<12672, 256, 0, stream>>>(hs, A_bf, 3244032, cs2, qa, ka, vt);
  k_cvt_t<<<dim3(22, 88), 256, 0, stream>>>(wqkv, wo, Bt1, Bt2);
  k_gemm<3><<<dim3(72, 33), 256, 0, stream>>>(A_bf, Bt1, bqkv, nullptr, 9216, 4224, 1408,
                                              qa, ka, vt, cs2);
  k_attn<<<dim3(256, 9), 256, 0, stream>>>(qa, ka, vt, A_bf);
  k_gemm<0><<<dim3(72, 11), 256, 0, stream>>>(A_bf, Bt2, bo, out, 9216, 1408, 1408,
                                              nullptr, nullptr, nullptr, nullptr);
}